// Round 1
// baseline (431.718 us; speedup 1.0000x reference)
//
#include <hip/hip_runtime.h>
#include <hip/hip_bf16.h>

// Problem constants (fixed by the reference: B=4,S=2048,D=1024,E=8,H=1024)
#define T_TOK 8192
#define DDIM  1024
#define NEXP  8
#define HDIM  1024
#define SLOT_CAP 17536   // 137 M-tiles * 128; >= 16384 + 8*127 padding worst case

typedef short bf16x8 __attribute__((ext_vector_type(8)));   // 8 bf16 in 4 VGPRs (guide §3)
typedef float f32x4  __attribute__((ext_vector_type(4)));

typedef const __attribute__((address_space(1))) unsigned int* gas_ptr;
typedef __attribute__((address_space(3))) unsigned int*       las_ptr;

#define GLD16(gp, lp) __builtin_amdgcn_global_load_lds((gas_ptr)(gp), (las_ptr)(lp), 16, 0, 0)

// fp32 -> bf16 round-to-nearest-even (inputs are finite Gaussians; no NaN path needed)
static __device__ __forceinline__ unsigned short f2b(float f) {
    union { float f; unsigned int u; } v; v.f = f;
    unsigned int u = v.u;
    u += 0x7fffu + ((u >> 16) & 1u);
    return (unsigned short)(u >> 16);
}

// ---------------------------------------------------------------------------
// K1: routing. One block per token: fp64 logits (tie-exact vs numpy ref),
// softmax top-2 renormalized, per-expert rank via atomicAdd. Also converts the
// x row to bf16 (fused: we're already streaming x).
// ---------------------------------------------------------------------------
__global__ __launch_bounds__(256) void moe_routing(
    const float* __restrict__ x, const float* __restrict__ wg,
    unsigned short* __restrict__ xb,
    int* __restrict__ counts,
    int* __restrict__ tok_e, int* __restrict__ tok_r, float* __restrict__ tok_g)
{
    int t   = blockIdx.x;
    int tid = threadIdx.x;

    float4 xv = ((const float4*)(x + (size_t)t * DDIM))[tid];
    ushort4 xs;
    xs.x = f2b(xv.x); xs.y = f2b(xv.y); xs.z = f2b(xv.z); xs.w = f2b(xv.w);
    ((ushort4*)(xb + (size_t)t * DDIM))[tid] = xs;

    double s[NEXP];
    #pragma unroll
    for (int e = 0; e < NEXP; e++) s[e] = 0.0;
    const float* wr = wg + (size_t)tid * 4 * NEXP;   // Wg rows d = 4*tid .. 4*tid+3
    #pragma unroll
    for (int j = 0; j < 4; j++) {
        double xj = (double)((&xv.x)[j]);
        #pragma unroll
        for (int e = 0; e < NEXP; e++)
            s[e] += xj * (double)wr[j * NEXP + e];
    }

    // wave (64-lane) shuffle reduce, then cross-wave via LDS
    #pragma unroll
    for (int off = 32; off > 0; off >>= 1)
        #pragma unroll
        for (int e = 0; e < NEXP; e++) s[e] += __shfl_down(s[e], off);

    __shared__ double red[4][NEXP];
    int lane = tid & 63, wv = tid >> 6;
    if (lane == 0)
        for (int e = 0; e < NEXP; e++) red[wv][e] = s[e];
    __syncthreads();

    if (tid == 0) {
        double l[NEXP];
        for (int e = 0; e < NEXP; e++)
            l[e] = red[0][e] + red[1][e] + red[2][e] + red[3][e];
        // top-2, first-index-on-tie (matches jax.lax.top_k)
        int e0 = 0;
        for (int e = 1; e < NEXP; e++) if (l[e] > l[e0]) e0 = e;
        int e1 = (e0 == 0) ? 1 : 0;
        for (int e = 0; e < NEXP; e++) if (e != e0 && l[e] > l[e1]) e1 = e;
        // renormalized top-2 softmax: full-softmax denominator cancels
        double g0 = 1.0 / (1.0 + exp(l[e1] - l[e0]));
        double g1 = 1.0 - g0;
        int r0 = atomicAdd(&counts[e0], 1);
        int r1 = atomicAdd(&counts[e1], 1);
        tok_e[2*t] = e0; tok_e[2*t+1] = e1;
        tok_r[2*t] = r0; tok_r[2*t+1] = r1;
        tok_g[2*t] = (float)g0; tok_g[2*t+1] = (float)g1;
    }
}

// K2: 128-aligned exclusive prefix over 8 expert counts (single thread).
__global__ void moe_offsets(const int* __restrict__ counts, int* __restrict__ meta) {
    if (threadIdx.x == 0 && blockIdx.x == 0) {
        int off = 0;
        for (int e = 0; e < NEXP; e++) {
            meta[e] = off;
            off += (counts[e] + 127) & ~127;
        }
        meta[NEXP] = off;   // padded total
    }
}

// K3: scatter token id + gate into per-expert slot arrays (pads stay -1).
__global__ __launch_bounds__(256) void moe_slotfill(
    const int* __restrict__ tok_e, const int* __restrict__ tok_r,
    const float* __restrict__ tok_g, const int* __restrict__ meta,
    int* __restrict__ slot_token, float* __restrict__ slot_gate)
{
    int t = blockIdx.x * 256 + threadIdx.x;
    if (t >= T_TOK) return;
    #pragma unroll
    for (int i = 0; i < 2; i++) {
        int e = tok_e[2*t + i];
        int s = meta[e] + tok_r[2*t + i];
        slot_token[s] = t;
        slot_gate[s]  = tok_g[2*t + i];
    }
}

// K4: We [E][D][H] fp32 -> Wt [E][H][D] bf16 (transpose so GEMM B-fragments
// are contiguous 16B ds_read_b128 loads). 64x64 tiles via LDS.
__global__ __launch_bounds__(256) void moe_wtrans(
    const float* __restrict__ we, unsigned short* __restrict__ wt)
{
    __shared__ unsigned short tile[64][65];   // odd ushort stride breaks bank aliasing
    int e  = blockIdx.z;
    int d0 = blockIdx.y * 64;
    int h0 = blockIdx.x * 64;
    int c  = threadIdx.x & 63;
    int r4 = threadIdx.x >> 6;
    #pragma unroll
    for (int i = 0; i < 64; i += 4)
        tile[r4 + i][c] = f2b(we[((size_t)e * DDIM + d0 + r4 + i) * HDIM + h0 + c]);
    __syncthreads();
    #pragma unroll
    for (int i = 0; i < 64; i += 4)
        wt[((size_t)e * HDIM + h0 + r4 + i) * DDIM + d0 + c] = tile[c][r4 + i];
}

// ---------------------------------------------------------------------------
// K5: grouped gather-GEMM. Grid (Ntiles=8, Mtiles=137). Block = 256 thr = 4
// waves, 128x128 C tile, BK=32, 16x16x32 bf16 MFMA, width-16 global_load_lds
// staging for both A (gathered token rows) and B (contiguous Wt rows).
// Epilogue: out[t][h] += gate * (acc + be[e][h]) via fp32 atomicAdd.
// ---------------------------------------------------------------------------
__global__ __launch_bounds__(256) void moe_gemm(
    const unsigned short* __restrict__ xb,   // [T][D] bf16
    const unsigned short* __restrict__ wt,   // [E][H][D] bf16
    const float* __restrict__ be,            // [E][H]
    const int* __restrict__ slot_token,
    const float* __restrict__ slot_gate,
    const int* __restrict__ meta,
    float* __restrict__ out)                 // [T][H] fp32, pre-zeroed
{
    __shared__ __align__(16) unsigned short As[128 * 32];
    __shared__ __align__(16) unsigned short Bs[128 * 32];

    int m0 = blockIdx.y * 128;
    if (m0 >= meta[NEXP]) return;            // uniform early-exit past padded total
    int n0 = blockIdx.x * 128;

    int e = 0;
    #pragma unroll
    for (int i = 1; i < NEXP; i++) if (m0 >= meta[i]) e = i;

    int tid  = threadIdx.x;
    int lane = tid & 63, wv = tid >> 6;

    // Staging layout: 8 chunks of 16 rows x 32 k (1 KB each); wave w owns
    // chunks 2w and 2w+1 for both A and B. Lane i -> row (lane>>2), 16B k-chunk (lane&3).
    int rowc = (wv * 2) * 16 + (lane >> 2);
    int kc   = (lane & 3) * 8;
    int tA0 = slot_token[m0 + rowc];
    int tA1 = slot_token[m0 + rowc + 16];
    if (tA0 < 0) tA0 = 0;                    // pad rows: load safe garbage, discarded later
    if (tA1 < 0) tA1 = 0;
    const unsigned short* gA0 = xb + (size_t)tA0 * DDIM + kc;
    const unsigned short* gA1 = xb + (size_t)tA1 * DDIM + kc;
    const unsigned short* gB0 = wt + ((size_t)e * HDIM + n0 + rowc) * DDIM + kc;
    const unsigned short* gB1 = gB0 + (size_t)16 * DDIM;
    unsigned short* lA0 = As + (wv * 2) * 512;   // wave-uniform LDS bases
    unsigned short* lA1 = lA0 + 512;
    unsigned short* lB0 = Bs + (wv * 2) * 512;
    unsigned short* lB1 = lB0 + 512;

    f32x4 acc[4][4];
    #pragma unroll
    for (int i = 0; i < 4; i++)
        #pragma unroll
        for (int j = 0; j < 4; j++) acc[i][j] = (f32x4){0.f, 0.f, 0.f, 0.f};

    int wm = (wv >> 1) * 64, wn = (wv & 1) * 64;
    int l16 = lane & 15, quad = lane >> 4;

    for (int k0 = 0; k0 < DDIM; k0 += 32) {
        GLD16(gA0 + k0, lA0);
        GLD16(gA1 + k0, lA1);
        GLD16(gB0 + k0, lB0);
        GLD16(gB1 + k0, lB1);
        __syncthreads();                      // drains vmcnt: staged data visible

        bf16x8 af[4], bfr[4];
        #pragma unroll
        for (int i = 0; i < 4; i++) {
            af[i]  = *(const bf16x8*)(As + (wm + i * 16 + l16) * 32 + quad * 8);
            bfr[i] = *(const bf16x8*)(Bs + (wn + i * 16 + l16) * 32 + quad * 8);
        }
        #pragma unroll
        for (int i = 0; i < 4; i++)
            #pragma unroll
            for (int j = 0; j < 4; j++)
                acc[i][j] = __builtin_amdgcn_mfma_f32_16x16x32_bf16(
                    af[i], bfr[j], acc[i][j], 0, 0, 0);
        __syncthreads();                      // protect LDS before next-iter staging
    }

    // Epilogue: C/D layout col=lane&15, row=quad*4+reg (measured m89/m91)
    #pragma unroll
    for (int i = 0; i < 4; i++) {
        #pragma unroll
        for (int r = 0; r < 4; r++) {
            int row  = wm + i * 16 + quad * 4 + r;
            int slot = m0 + row;
            int t = slot_token[slot];
            if (t < 0) continue;              // padding slot
            float g = slot_gate[slot];
            float* op = out + (size_t)t * HDIM + n0;
            #pragma unroll
            for (int j = 0; j < 4; j++) {
                int col = wn + j * 16 + l16;
                atomicAdd(op + col, g * (acc[i][j][r] + be[e * HDIM + n0 + col]));
            }
        }
    }
}

extern "C" void kernel_launch(void* const* d_in, const int* in_sizes, int n_in,
                              void* d_out, int out_size, void* d_ws, size_t ws_size,
                              hipStream_t stream) {
    const float* x  = (const float*)d_in[0];   // [B,S,D] fp32
    const float* wg = (const float*)d_in[1];   // [D,E]
    const float* we = (const float*)d_in[2];   // [E,D,H]
    const float* be = (const float*)d_in[3];   // [E,H]
    float* out = (float*)d_out;

    char* ws = (char*)d_ws;
    size_t o = 0;
    auto alloc = [&](size_t bytes) -> void* {
        void* p = ws + o;
        o = (o + bytes + 255) & ~(size_t)255;
        return p;
    };
    unsigned short* xb   = (unsigned short*)alloc((size_t)T_TOK * DDIM * 2);
    unsigned short* wtb  = (unsigned short*)alloc((size_t)NEXP * HDIM * DDIM * 2);
    int*   slot_token    = (int*)  alloc((size_t)SLOT_CAP * 4);
    float* slot_gate     = (float*)alloc((size_t)SLOT_CAP * 4);
    int*   counts        = (int*)  alloc(NEXP * 4);
    int*   meta          = (int*)  alloc((NEXP + 1) * 4);
    int*   tok_e         = (int*)  alloc((size_t)T_TOK * 2 * 4);
    int*   tok_r         = (int*)  alloc((size_t)T_TOK * 2 * 4);
    float* tok_g         = (float*)alloc((size_t)T_TOK * 2 * 4);

    hipMemsetAsync(counts, 0, NEXP * 4, stream);
    hipMemsetAsync(slot_token, 0xFF, (size_t)SLOT_CAP * 4, stream);   // -1 = pad
    hipMemsetAsync(d_out, 0, (size_t)out_size * 4, stream);

    moe_routing<<<T_TOK, 256, 0, stream>>>(x, wg, xb, counts, tok_e, tok_r, tok_g);
    moe_offsets<<<1, 64, 0, stream>>>(counts, meta);
    moe_slotfill<<<T_TOK / 256, 256, 0, stream>>>(tok_e, tok_r, tok_g, meta,
                                                  slot_token, slot_gate);
    moe_wtrans<<<dim3(HDIM / 64, DDIM / 64, NEXP), 256, 0, stream>>>(we, wtb);
    moe_gemm<<<dim3(HDIM / 128, SLOT_CAP / 128), 256, 0, stream>>>(
        xb, wtb, be, slot_token, slot_gate, meta, out);
}

// Round 2
// 282.169 us; speedup vs baseline: 1.5300x; 1.5300x over previous
//
#include <hip/hip_runtime.h>
#include <hip/hip_bf16.h>

// Problem constants (fixed by the reference: B=4,S=2048,D=1024,E=8,H=1024)
#define T_TOK 8192
#define DDIM  1024
#define NEXP  8
#define HDIM  1024
#define SLOT_CAP 17536   // 137 M-tiles * 128; >= 16384 + 8*127 padding worst case

typedef short bf16x8 __attribute__((ext_vector_type(8)));   // 8 bf16 in 4 VGPRs (guide §3)
typedef float f32x4  __attribute__((ext_vector_type(4)));

typedef const __attribute__((address_space(1))) unsigned int* gas_ptr;
typedef __attribute__((address_space(3))) unsigned int*       las_ptr;

#define GLD16(gp, lp) __builtin_amdgcn_global_load_lds((gas_ptr)(gp), (las_ptr)(lp), 16, 0, 0)

// fp32 -> bf16 round-to-nearest-even (inputs are finite Gaussians; no NaN path needed)
static __device__ __forceinline__ unsigned short f2b(float f) {
    union { float f; unsigned int u; } v; v.f = f;
    unsigned int u = v.u;
    u += 0x7fffu + ((u >> 16) & 1u);
    return (unsigned short)(u >> 16);
}

// ---------------------------------------------------------------------------
// K1: routing. One block per token: fp64 logits (tie-exact vs numpy ref),
// softmax top-2 renormalized. NO GLOBAL ATOMICS (R1 lesson: 16384 contended
// same-line atomics serialized at ~12 ns each = 198 us). Also converts the
// x row to bf16 (fused: we're already streaming x).
// ---------------------------------------------------------------------------
__global__ __launch_bounds__(256) void moe_routing(
    const float* __restrict__ x, const float* __restrict__ wg,
    unsigned short* __restrict__ xb,
    int* __restrict__ tok_e, float* __restrict__ tok_g)
{
    int t   = blockIdx.x;
    int tid = threadIdx.x;

    float4 xv = ((const float4*)(x + (size_t)t * DDIM))[tid];
    ushort4 xs;
    xs.x = f2b(xv.x); xs.y = f2b(xv.y); xs.z = f2b(xv.z); xs.w = f2b(xv.w);
    ((ushort4*)(xb + (size_t)t * DDIM))[tid] = xs;

    double s[NEXP];
    #pragma unroll
    for (int e = 0; e < NEXP; e++) s[e] = 0.0;
    const float* wr = wg + (size_t)tid * 4 * NEXP;   // Wg rows d = 4*tid .. 4*tid+3
    #pragma unroll
    for (int j = 0; j < 4; j++) {
        double xj = (double)((&xv.x)[j]);
        #pragma unroll
        for (int e = 0; e < NEXP; e++)
            s[e] += xj * (double)wr[j * NEXP + e];
    }

    // wave (64-lane) shuffle reduce, then cross-wave via LDS
    #pragma unroll
    for (int off = 32; off > 0; off >>= 1)
        #pragma unroll
        for (int e = 0; e < NEXP; e++) s[e] += __shfl_down(s[e], off);

    __shared__ double red[4][NEXP];
    int lane = tid & 63, wv = tid >> 6;
    if (lane == 0)
        for (int e = 0; e < NEXP; e++) red[wv][e] = s[e];
    __syncthreads();

    if (tid == 0) {
        double l[NEXP];
        for (int e = 0; e < NEXP; e++)
            l[e] = red[0][e] + red[1][e] + red[2][e] + red[3][e];
        // top-2, first-index-on-tie (matches jax.lax.top_k)
        int e0 = 0;
        for (int e = 1; e < NEXP; e++) if (l[e] > l[e0]) e0 = e;
        int e1 = (e0 == 0) ? 1 : 0;
        for (int e = 0; e < NEXP; e++) if (e != e0 && l[e] > l[e1]) e1 = e;
        // renormalized top-2 softmax: full-softmax denominator cancels
        double g0 = 1.0 / (1.0 + exp(l[e1] - l[e0]));
        double g1 = 1.0 - g0;
        tok_e[2*t] = e0; tok_e[2*t+1] = e1;
        tok_g[2*t] = (float)g0; tok_g[2*t+1] = (float)g1;
    }
}

// K1b: per-expert histogram. 32 blocks x 256 thr (1 token/thr), LDS hist,
// then 8 global atomics per block (256 total vs 16384 before).
__global__ __launch_bounds__(256) void moe_count(
    const int* __restrict__ tok_e, int* __restrict__ counts)
{
    __shared__ int h[NEXP];
    if (threadIdx.x < NEXP) h[threadIdx.x] = 0;
    __syncthreads();
    int t = blockIdx.x * 256 + threadIdx.x;
    atomicAdd(&h[tok_e[2*t]], 1);
    atomicAdd(&h[tok_e[2*t+1]], 1);
    __syncthreads();
    if (threadIdx.x < NEXP) atomicAdd(&counts[threadIdx.x], h[threadIdx.x]);
}

// K2: 128-aligned exclusive prefix over 8 expert counts; init per-expert cursors.
__global__ void moe_offsets(const int* __restrict__ counts, int* __restrict__ meta,
                            int* __restrict__ cursor) {
    if (threadIdx.x == 0 && blockIdx.x == 0) {
        int off = 0;
        for (int e = 0; e < NEXP; e++) {
            meta[e] = off;
            cursor[e] = off;
            off += (counts[e] + 127) & ~127;
        }
        meta[NEXP] = off;   // padded total
    }
}

// K3: slot assignment. Per-block LDS-atomic local ranks + one global cursor
// bump per expert per block (8 x 32 = 256 global atomics). Pads stay -1.
__global__ __launch_bounds__(256) void moe_slotfill(
    const int* __restrict__ tok_e, const float* __restrict__ tok_g,
    int* __restrict__ cursor,
    int* __restrict__ slot_token, float* __restrict__ slot_gate)
{
    __shared__ int h[NEXP];
    __shared__ int base[NEXP];
    if (threadIdx.x < NEXP) h[threadIdx.x] = 0;
    __syncthreads();
    int t = blockIdx.x * 256 + threadIdx.x;
    int e0 = tok_e[2*t],     e1 = tok_e[2*t + 1];
    int r0 = atomicAdd(&h[e0], 1);
    int r1 = atomicAdd(&h[e1], 1);
    __syncthreads();
    if (threadIdx.x < NEXP)
        base[threadIdx.x] = atomicAdd(&cursor[threadIdx.x], h[threadIdx.x]);
    __syncthreads();
    int s0 = base[e0] + r0, s1 = base[e1] + r1;
    slot_token[s0] = t; slot_gate[s0] = tok_g[2*t];
    slot_token[s1] = t; slot_gate[s1] = tok_g[2*t + 1];
}

// K4: We [E][D][H] fp32 -> Wt [E][H][D] bf16 (transpose so GEMM B-fragments
// are contiguous 16B ds_read_b128 loads). 64x64 tiles via LDS.
__global__ __launch_bounds__(256) void moe_wtrans(
    const float* __restrict__ we, unsigned short* __restrict__ wt)
{
    __shared__ unsigned short tile[64][65];   // odd ushort stride breaks bank aliasing
    int e  = blockIdx.z;
    int d0 = blockIdx.y * 64;
    int h0 = blockIdx.x * 64;
    int c  = threadIdx.x & 63;
    int r4 = threadIdx.x >> 6;
    #pragma unroll
    for (int i = 0; i < 64; i += 4)
        tile[r4 + i][c] = f2b(we[((size_t)e * DDIM + d0 + r4 + i) * HDIM + h0 + c]);
    __syncthreads();
    #pragma unroll
    for (int i = 0; i < 64; i += 4)
        wt[((size_t)e * HDIM + h0 + r4 + i) * DDIM + d0 + c] = tile[c][r4 + i];
}

// ---------------------------------------------------------------------------
// K5: grouped gather-GEMM. Grid (Ntiles=8, Mtiles=137). Block = 256 thr = 4
// waves, 128x128 C tile, BK=32, 16x16x32 bf16 MFMA, width-16 global_load_lds
// staging for both A (gathered token rows) and B (contiguous Wt rows).
// Epilogue: out[t][h] += gate * (acc + be[e][h]) via fp32 atomicAdd.
// ---------------------------------------------------------------------------
__global__ __launch_bounds__(256) void moe_gemm(
    const unsigned short* __restrict__ xb,   // [T][D] bf16
    const unsigned short* __restrict__ wt,   // [E][H][D] bf16
    const float* __restrict__ be,            // [E][H]
    const int* __restrict__ slot_token,
    const float* __restrict__ slot_gate,
    const int* __restrict__ meta,
    float* __restrict__ out)                 // [T][H] fp32, pre-zeroed
{
    __shared__ __align__(16) unsigned short As[128 * 32];
    __shared__ __align__(16) unsigned short Bs[128 * 32];

    int m0 = blockIdx.y * 128;
    if (m0 >= meta[NEXP]) return;            // uniform early-exit past padded total
    int n0 = blockIdx.x * 128;

    int e = 0;
    #pragma unroll
    for (int i = 1; i < NEXP; i++) if (m0 >= meta[i]) e = i;

    int tid  = threadIdx.x;
    int lane = tid & 63, wv = tid >> 6;

    // Staging layout: 8 chunks of 16 rows x 32 k (1 KB each); wave w owns
    // chunks 2w and 2w+1 for both A and B. Lane i -> row (lane>>2), 16B k-chunk (lane&3).
    int rowc = (wv * 2) * 16 + (lane >> 2);
    int kc   = (lane & 3) * 8;
    int tA0 = slot_token[m0 + rowc];
    int tA1 = slot_token[m0 + rowc + 16];
    if (tA0 < 0) tA0 = 0;                    // pad rows: load safe garbage, discarded later
    if (tA1 < 0) tA1 = 0;
    const unsigned short* gA0 = xb + (size_t)tA0 * DDIM + kc;
    const unsigned short* gA1 = xb + (size_t)tA1 * DDIM + kc;
    const unsigned short* gB0 = wt + ((size_t)e * HDIM + n0 + rowc) * DDIM + kc;
    const unsigned short* gB1 = gB0 + (size_t)16 * DDIM;
    unsigned short* lA0 = As + (wv * 2) * 512;   // wave-uniform LDS bases
    unsigned short* lA1 = lA0 + 512;
    unsigned short* lB0 = Bs + (wv * 2) * 512;
    unsigned short* lB1 = lB0 + 512;

    f32x4 acc[4][4];
    #pragma unroll
    for (int i = 0; i < 4; i++)
        #pragma unroll
        for (int j = 0; j < 4; j++) acc[i][j] = (f32x4){0.f, 0.f, 0.f, 0.f};

    int wm = (wv >> 1) * 64, wn = (wv & 1) * 64;
    int l16 = lane & 15, quad = lane >> 4;

    for (int k0 = 0; k0 < DDIM; k0 += 32) {
        GLD16(gA0 + k0, lA0);
        GLD16(gA1 + k0, lA1);
        GLD16(gB0 + k0, lB0);
        GLD16(gB1 + k0, lB1);
        __syncthreads();                      // drains vmcnt: staged data visible

        bf16x8 af[4], bfr[4];
        #pragma unroll
        for (int i = 0; i < 4; i++) {
            af[i]  = *(const bf16x8*)(As + (wm + i * 16 + l16) * 32 + quad * 8);
            bfr[i] = *(const bf16x8*)(Bs + (wn + i * 16 + l16) * 32 + quad * 8);
        }
        #pragma unroll
        for (int i = 0; i < 4; i++)
            #pragma unroll
            for (int j = 0; j < 4; j++)
                acc[i][j] = __builtin_amdgcn_mfma_f32_16x16x32_bf16(
                    af[i], bfr[j], acc[i][j], 0, 0, 0);
        __syncthreads();                      // protect LDS before next-iter staging
    }

    // Epilogue: C/D layout col=lane&15, row=quad*4+reg (measured m89/m91)
    #pragma unroll
    for (int i = 0; i < 4; i++) {
        #pragma unroll
        for (int r = 0; r < 4; r++) {
            int row  = wm + i * 16 + quad * 4 + r;
            int slot = m0 + row;
            int t = slot_token[slot];
            if (t < 0) continue;              // padding slot
            float g = slot_gate[slot];
            float* op = out + (size_t)t * HDIM + n0;
            #pragma unroll
            for (int j = 0; j < 4; j++) {
                int col = wn + j * 16 + l16;
                atomicAdd(op + col, g * (acc[i][j][r] + be[e * HDIM + n0 + col]));
            }
        }
    }
}

extern "C" void kernel_launch(void* const* d_in, const int* in_sizes, int n_in,
                              void* d_out, int out_size, void* d_ws, size_t ws_size,
                              hipStream_t stream) {
    const float* x  = (const float*)d_in[0];   // [B,S,D] fp32
    const float* wg = (const float*)d_in[1];   // [D,E]
    const float* we = (const float*)d_in[2];   // [E,D,H]
    const float* be = (const float*)d_in[3];   // [E,H]
    float* out = (float*)d_out;

    char* ws = (char*)d_ws;
    size_t o = 0;
    auto alloc = [&](size_t bytes) -> void* {
        void* p = ws + o;
        o = (o + bytes + 255) & ~(size_t)255;
        return p;
    };
    unsigned short* xb   = (unsigned short*)alloc((size_t)T_TOK * DDIM * 2);
    unsigned short* wtb  = (unsigned short*)alloc((size_t)NEXP * HDIM * DDIM * 2);
    int*   slot_token    = (int*)  alloc((size_t)SLOT_CAP * 4);
    float* slot_gate     = (float*)alloc((size_t)SLOT_CAP * 4);
    int*   counts        = (int*)  alloc(NEXP * 4);
    int*   meta          = (int*)  alloc((NEXP + 1) * 4);
    int*   cursor        = (int*)  alloc(NEXP * 4);
    int*   tok_e         = (int*)  alloc((size_t)T_TOK * 2 * 4);
    float* tok_g         = (float*)alloc((size_t)T_TOK * 2 * 4);

    hipMemsetAsync(counts, 0, NEXP * 4, stream);
    hipMemsetAsync(slot_token, 0xFF, (size_t)SLOT_CAP * 4, stream);   // -1 = pad
    hipMemsetAsync(d_out, 0, (size_t)out_size * 4, stream);

    moe_routing<<<T_TOK, 256, 0, stream>>>(x, wg, xb, tok_e, tok_g);
    moe_count<<<T_TOK / 256, 256, 0, stream>>>(tok_e, counts);
    moe_offsets<<<1, 64, 0, stream>>>(counts, meta, cursor);
    moe_slotfill<<<T_TOK / 256, 256, 0, stream>>>(tok_e, tok_g, cursor,
                                                  slot_token, slot_gate);
    moe_wtrans<<<dim3(HDIM / 64, DDIM / 64, NEXP), 256, 0, stream>>>(we, wtb);
    moe_gemm<<<dim3(HDIM / 128, SLOT_CAP / 128), 256, 0, stream>>>(
        xb, wtb, be, slot_token, slot_gate, meta, out);
}

// Round 3
// 269.003 us; speedup vs baseline: 1.6049x; 1.0489x over previous
//
#include <hip/hip_runtime.h>
#include <hip/hip_bf16.h>

// Problem constants (fixed by the reference: B=4,S=2048,D=1024,E=8,H=1024)
#define T_TOK 8192
#define DDIM  1024
#define NEXP  8
#define HDIM  1024
#define SLOT_CAP 17536   // 137 M-tiles * 128; >= 16384 + 8*127 padding worst case

typedef short bf16x8 __attribute__((ext_vector_type(8)));   // 8 bf16 in 4 VGPRs
typedef float f32x4  __attribute__((ext_vector_type(4)));

// fp32 -> bf16 round-to-nearest-even
static __device__ __forceinline__ unsigned short f2b(float f) {
    union { float f; unsigned int u; } v; v.f = f;
    unsigned int u = v.u;
    u += 0x7fffu + ((u >> 16) & 1u);
    return (unsigned short)(u >> 16);
}

// ---------------------------------------------------------------------------
// K1: routing. One block per token: fp64 logits (selection-exact), softmax
// top-2 renormalized. R2 lesson: 48 fp64 __shfl_down per thread = ~200M
// ds-permute lane-ops kernel-wide. Replaced with a 2-stage LDS reduction
// (pad 9 doubles/row to spread banks). Also fused x -> bf16 conversion.
// ---------------------------------------------------------------------------
__global__ __launch_bounds__(256) void moe_routing(
    const float* __restrict__ x, const float* __restrict__ wg,
    unsigned short* __restrict__ xb,
    int* __restrict__ tok_e, float* __restrict__ tok_g)
{
    __shared__ double red[256 * 9];   // [thread][expert], stride 9 (bank spread)
    __shared__ double part[64];
    __shared__ double lf[NEXP];

    int t   = blockIdx.x;
    int tid = threadIdx.x;

    float4 xv = ((const float4*)(x + (size_t)t * DDIM))[tid];
    ushort4 xs;
    xs.x = f2b(xv.x); xs.y = f2b(xv.y); xs.z = f2b(xv.z); xs.w = f2b(xv.w);
    ((ushort4*)(xb + (size_t)t * DDIM))[tid] = xs;

    double s[NEXP];
    #pragma unroll
    for (int e = 0; e < NEXP; e++) s[e] = 0.0;
    const float* wr = wg + (size_t)tid * 4 * NEXP;   // Wg rows d = 4*tid .. 4*tid+3
    #pragma unroll
    for (int j = 0; j < 4; j++) {
        double xj = (double)((&xv.x)[j]);
        #pragma unroll
        for (int e = 0; e < NEXP; e++)
            s[e] += xj * (double)wr[j * NEXP + e];
    }
    #pragma unroll
    for (int e = 0; e < NEXP; e++) red[tid * 9 + e] = s[e];
    __syncthreads();

    if (tid < 64) {                    // stage B: 8 partials per expert
        int e = tid >> 3, p = tid & 7;
        double acc = 0.0;
        for (int i = 0; i < 32; i++) acc += red[(i * 8 + p) * 9 + e];
        part[tid] = acc;
    }
    __syncthreads();
    if (tid < NEXP) {                  // stage C: final 8 -> 1 per expert
        double acc = 0.0;
        #pragma unroll
        for (int p = 0; p < 8; p++) acc += part[tid * 8 + p];
        lf[tid] = acc;
    }
    __syncthreads();

    if (tid == 0) {
        double l[NEXP];
        #pragma unroll
        for (int e = 0; e < NEXP; e++) l[e] = lf[e];
        // top-2, first-index-on-tie (matches jax.lax.top_k)
        int e0 = 0;
        for (int e = 1; e < NEXP; e++) if (l[e] > l[e0]) e0 = e;
        int e1 = (e0 == 0) ? 1 : 0;
        for (int e = 0; e < NEXP; e++) if (e != e0 && l[e] > l[e1]) e1 = e;
        double g0 = 1.0 / (1.0 + exp(l[e1] - l[e0]));   // renorm top-2 softmax
        double g1 = 1.0 - g0;
        tok_e[2*t] = e0; tok_e[2*t+1] = e1;
        tok_g[2*t] = (float)g0; tok_g[2*t+1] = (float)g1;
    }
}

// K1b: per-expert histogram. LDS hist then 8 global atomics per block.
__global__ __launch_bounds__(256) void moe_count(
    const int* __restrict__ tok_e, int* __restrict__ counts)
{
    __shared__ int h[NEXP];
    if (threadIdx.x < NEXP) h[threadIdx.x] = 0;
    __syncthreads();
    int t = blockIdx.x * 256 + threadIdx.x;
    atomicAdd(&h[tok_e[2*t]], 1);
    atomicAdd(&h[tok_e[2*t+1]], 1);
    __syncthreads();
    if (threadIdx.x < NEXP) atomicAdd(&counts[threadIdx.x], h[threadIdx.x]);
}

// K2: 128-aligned exclusive prefix over 8 expert counts; init cursors.
__global__ void moe_offsets(const int* __restrict__ counts, int* __restrict__ meta,
                            int* __restrict__ cursor) {
    if (threadIdx.x == 0 && blockIdx.x == 0) {
        int off = 0;
        for (int e = 0; e < NEXP; e++) {
            meta[e] = off;
            cursor[e] = off;
            off += (counts[e] + 127) & ~127;
        }
        meta[NEXP] = off;   // padded total
    }
}

// K3: slot assignment. LDS-atomic local ranks + one cursor bump/expert/block.
__global__ __launch_bounds__(256) void moe_slotfill(
    const int* __restrict__ tok_e, const float* __restrict__ tok_g,
    int* __restrict__ cursor,
    int* __restrict__ slot_token, float* __restrict__ slot_gate)
{
    __shared__ int h[NEXP];
    __shared__ int base[NEXP];
    if (threadIdx.x < NEXP) h[threadIdx.x] = 0;
    __syncthreads();
    int t = blockIdx.x * 256 + threadIdx.x;
    int e0 = tok_e[2*t],     e1 = tok_e[2*t + 1];
    int r0 = atomicAdd(&h[e0], 1);
    int r1 = atomicAdd(&h[e1], 1);
    __syncthreads();
    if (threadIdx.x < NEXP)
        base[threadIdx.x] = atomicAdd(&cursor[threadIdx.x], h[threadIdx.x]);
    __syncthreads();
    int s0 = base[e0] + r0, s1 = base[e1] + r1;
    slot_token[s0] = t; slot_gate[s0] = tok_g[2*t];
    slot_token[s1] = t; slot_gate[s1] = tok_g[2*t + 1];
}

// K4: We [E][D][H] fp32 -> Wt [E][H][D] bf16 (transpose for GEMM B loads).
__global__ __launch_bounds__(256) void moe_wtrans(
    const float* __restrict__ we, unsigned short* __restrict__ wt)
{
    __shared__ unsigned short tile[64][65];
    int e  = blockIdx.z;
    int d0 = blockIdx.y * 64;
    int h0 = blockIdx.x * 64;
    int c  = threadIdx.x & 63;
    int r4 = threadIdx.x >> 6;
    #pragma unroll
    for (int i = 0; i < 64; i += 4)
        tile[r4 + i][c] = f2b(we[((size_t)e * DDIM + d0 + r4 + i) * HDIM + h0 + c]);
    __syncthreads();
    #pragma unroll
    for (int i = 0; i < 64; i += 4)
        wt[((size_t)e * HDIM + h0 + r4 + i) * DDIM + d0 + c] = tile[c][r4 + i];
}

// ---------------------------------------------------------------------------
// K5: grouped gather-GEMM, software-pipelined (R2 lesson: single-buffer
// global_load_lds + vmcnt(0) drain per iter -> MfmaUtil 11%).
// Pipeline: regs hold tile k at loop top; ds_write (waits loads issued one
// full iter earlier) -> issue loads k+1 -> ONE barrier -> ds_read+MFMA.
// Double-buffered LDS makes the single barrier sufficient (reads of buf b at
// iter k complete before any wave's writes to buf b at iter k+2: each wave's
// MFMA lgkm-waits its reads before reaching barrier k+1).
// LDS k-chunk XOR swizzle (phys = c ^ ((row>>1)&3)): frag ds_read_b128 goes
// 8-way -> 2-way banked (free per m136).
// ---------------------------------------------------------------------------
__global__ __launch_bounds__(256) void moe_gemm(
    const unsigned short* __restrict__ xb,   // [T][D] bf16
    const unsigned short* __restrict__ wt,   // [E][H][D] bf16
    const float* __restrict__ be,            // [E][H]
    const int* __restrict__ slot_token,
    const float* __restrict__ slot_gate,
    const int* __restrict__ meta,
    float* __restrict__ out)                 // [T][H] fp32, pre-zeroed
{
    __shared__ __align__(16) unsigned short As[2][128 * 32];
    __shared__ __align__(16) unsigned short Bs[2][128 * 32];

    int m0 = blockIdx.y * 128;
    if (m0 >= meta[NEXP]) return;
    int n0 = blockIdx.x * 128;

    int e = 0;
    #pragma unroll
    for (int i = 1; i < NEXP; i++) if (m0 >= meta[i]) e = i;

    int tid  = threadIdx.x;
    int lane = tid & 63, wv = tid >> 6;

    // Staging: thread t handles rows r0=t>>2 and r0+64, 16B k-chunk c=t&3.
    int r0  = tid >> 2, c = tid & 3;
    int kus = c * 8;                          // ushort offset inside 32-k slab
    int tA0 = slot_token[m0 + r0];       if (tA0 < 0) tA0 = 0;
    int tA1 = slot_token[m0 + r0 + 64];  if (tA1 < 0) tA1 = 0;
    const unsigned short* gA0 = xb + (size_t)tA0 * DDIM + kus;
    const unsigned short* gA1 = xb + (size_t)tA1 * DDIM + kus;
    const unsigned short* gB0 = wt + ((size_t)e * HDIM + n0 + r0) * DDIM + kus;
    const unsigned short* gB1 = gB0 + (size_t)64 * DDIM;
    // swizzled LDS write offset; f(r0+64)==f(r0) so row+64 is just +2048
    int w0 = r0 * 32 + ((c ^ ((r0 >> 1) & 3)) * 8);

    f32x4 acc[4][4];
    #pragma unroll
    for (int i = 0; i < 4; i++)
        #pragma unroll
        for (int j = 0; j < 4; j++) acc[i][j] = (f32x4){0.f, 0.f, 0.f, 0.f};

    int wm = (wv >> 1) * 64, wn = (wv & 1) * 64;
    int l16 = lane & 15, quad = lane >> 4;
    int f = (l16 >> 1) & 3;                   // == (row>>1)&3 for all frag rows
    int rdA[4], rdB[4];
    #pragma unroll
    for (int i = 0; i < 4; i++) {
        rdA[i] = (wm + i * 16 + l16) * 32 + ((quad ^ f) * 8);
        rdB[i] = (wn + i * 16 + l16) * 32 + ((quad ^ f) * 8);
    }

    // prefetch k=0
    bf16x8 pa0 = *(const bf16x8*)(gA0);
    bf16x8 pa1 = *(const bf16x8*)(gA1);
    bf16x8 pb0 = *(const bf16x8*)(gB0);
    bf16x8 pb1 = *(const bf16x8*)(gB1);

    for (int k = 0; k < 32; ++k) {
        unsigned short* A = As[k & 1];
        unsigned short* B = Bs[k & 1];
        *(bf16x8*)(A + w0)        = pa0;      // waits vmcnt on loads from iter k-1
        *(bf16x8*)(A + w0 + 2048) = pa1;
        *(bf16x8*)(B + w0)        = pb0;
        *(bf16x8*)(B + w0 + 2048) = pb1;
        if (k + 1 < 32) {
            int ko = (k + 1) * 32;            // next 32-k slab (ushorts)
            pa0 = *(const bf16x8*)(gA0 + ko);
            pa1 = *(const bf16x8*)(gA1 + ko);
            pb0 = *(const bf16x8*)(gB0 + ko);
            pb1 = *(const bf16x8*)(gB1 + ko);
        }
        __syncthreads();                      // buf (k&1) ready for all waves

        bf16x8 af[4], bfr[4];
        #pragma unroll
        for (int i = 0; i < 4; i++) {
            af[i]  = *(const bf16x8*)(A + rdA[i]);
            bfr[i] = *(const bf16x8*)(B + rdB[i]);
        }
        #pragma unroll
        for (int i = 0; i < 4; i++)
            #pragma unroll
            for (int j = 0; j < 4; j++)
                acc[i][j] = __builtin_amdgcn_mfma_f32_16x16x32_bf16(
                    af[i], bfr[j], acc[i][j], 0, 0, 0);
    }

    // Epilogue: C/D layout col=lane&15, row=quad*4+reg (m89/m91)
    #pragma unroll
    for (int i = 0; i < 4; i++) {
        #pragma unroll
        for (int r = 0; r < 4; r++) {
            int row  = wm + i * 16 + quad * 4 + r;
            int slot = m0 + row;
            int t = slot_token[slot];
            if (t < 0) continue;              // padding slot
            float g = slot_gate[slot];
            float* op = out + (size_t)t * HDIM + n0;
            #pragma unroll
            for (int j = 0; j < 4; j++) {
                int col = wn + j * 16 + l16;
                atomicAdd(op + col, g * (acc[i][j][r] + be[e * HDIM + n0 + col]));
            }
        }
    }
}

extern "C" void kernel_launch(void* const* d_in, const int* in_sizes, int n_in,
                              void* d_out, int out_size, void* d_ws, size_t ws_size,
                              hipStream_t stream) {
    const float* x  = (const float*)d_in[0];   // [B,S,D] fp32
    const float* wg = (const float*)d_in[1];   // [D,E]
    const float* we = (const float*)d_in[2];   // [E,D,H]
    const float* be = (const float*)d_in[3];   // [E,H]
    float* out = (float*)d_out;

    char* ws = (char*)d_ws;
    size_t o = 0;
    auto alloc = [&](size_t bytes) -> void* {
        void* p = ws + o;
        o = (o + bytes + 255) & ~(size_t)255;
        return p;
    };
    unsigned short* xb   = (unsigned short*)alloc((size_t)T_TOK * DDIM * 2);
    unsigned short* wtb  = (unsigned short*)alloc((size_t)NEXP * HDIM * DDIM * 2);
    int*   slot_token    = (int*)  alloc((size_t)SLOT_CAP * 4);
    float* slot_gate     = (float*)alloc((size_t)SLOT_CAP * 4);
    int*   counts        = (int*)  alloc(NEXP * 4);
    int*   meta          = (int*)  alloc((NEXP + 1) * 4);
    int*   cursor        = (int*)  alloc(NEXP * 4);
    int*   tok_e         = (int*)  alloc((size_t)T_TOK * 2 * 4);
    float* tok_g         = (float*)alloc((size_t)T_TOK * 2 * 4);

    hipMemsetAsync(counts, 0, NEXP * 4, stream);
    hipMemsetAsync(slot_token, 0xFF, (size_t)SLOT_CAP * 4, stream);   // -1 = pad
    hipMemsetAsync(d_out, 0, (size_t)out_size * 4, stream);

    moe_routing<<<T_TOK, 256, 0, stream>>>(x, wg, xb, tok_e, tok_g);
    moe_count<<<T_TOK / 256, 256, 0, stream>>>(tok_e, counts);
    moe_offsets<<<1, 64, 0, stream>>>(counts, meta, cursor);
    moe_slotfill<<<T_TOK / 256, 256, 0, stream>>>(tok_e, tok_g, cursor,
                                                  slot_token, slot_gate);
    moe_wtrans<<<dim3(HDIM / 64, DDIM / 64, NEXP), 256, 0, stream>>>(we, wtb);
    moe_gemm<<<dim3(HDIM / 128, SLOT_CAP / 128), 256, 0, stream>>>(
        xb, wtb, be, slot_token, slot_gate, meta, out);
}